// Round 1
// baseline (749.079 us; speedup 1.0000x reference)
//
#include <hip/hip_runtime.h>

// ShawRelativePositionalEmbedding on MI355X (gfx950).
//
// out[bh][n][r] = (1/8) * sum_d q[bh][n][d] * E[n - r + 2048][d]
//   q:   [32, 2048, 64] fp32   (b*h flattened)
//   E:   [4097, 64]     fp32   (rel_pos_emb; k input is unused)
//   out: [32, 2048, 2048] fp32  (537 MB -> write-bandwidth bound, ~85us floor)
//
// Diagonal substitution u = n - r + 2048 turns this into a banded GEMM
// C[n][u] = Q[n,:] . E[u,:]^T, band u in [n+1, n+2048]. bf16 MFMA
// (16x16x32, fp32 accum) makes compute (~17 GFLOP) negligible vs writes.
//
// Block = 256 thr (4 waves), owns (bh, 64-row n-tile). A fragments (Q rows,
// converted fp32->bf16 RNE in registers) are loaded ONCE and held across the
// whole u sweep. Wave w owns u columns [16w,16w+16) of each 64-wide u-tile;
// j-loop slides u0 = n0 + 64j, j = 0..32, covering exactly the band.
// B fragment (16 E-rows) is reused across 4 n-subtiles -> B traffic ~540 MB
// total, L1/L2-served. No LDS, no __syncthreads.

#define NSEQ 2048
#define MAXS 2048

typedef short bf16x8 __attribute__((ext_vector_type(8)));  // 8 bf16 in 4 VGPRs
typedef float f32x4  __attribute__((ext_vector_type(4)));

__device__ __forceinline__ short f2bf(float f) {
    union { float f; unsigned u; } v; v.f = f;
    unsigned r = v.u + 0x7fffu + ((v.u >> 16) & 1u);   // round-to-nearest-even
    return (short)(r >> 16);
}

__device__ __forceinline__ bf16x8 load_cvt8(const float* p) {
    // 8 consecutive fp32 -> 8 bf16 (two dwordx4 loads)
    float4 x = *(const float4*)(p);
    float4 y = *(const float4*)(p + 4);
    bf16x8 f;
    f[0] = f2bf(x.x); f[1] = f2bf(x.y); f[2] = f2bf(x.z); f[3] = f2bf(x.w);
    f[4] = f2bf(y.x); f[5] = f2bf(y.y); f[6] = f2bf(y.z); f[7] = f2bf(y.w);
    return f;
}

__global__ __launch_bounds__(256, 4)
void shaw_rel_pos_kernel(const float* __restrict__ q,
                         const float* __restrict__ emb,
                         float* __restrict__ out) {
    const int n0   = blockIdx.x * 64;   // n-tile base (32 tiles)
    const int bh   = blockIdx.y;        // 0..31
    const int wave = threadIdx.x >> 6;  // 0..3, owns u columns [16w, 16w+16)
    const int lane = threadIdx.x & 63;
    const int l16  = lane & 15;
    const int quad = lane >> 4;

    // ---- A fragments: 4 n-subtiles x 2 k-steps, resident all kernel.
    // A-operand layout (16x16x32): A[m = lane&15][k = quad*8 + j].
    bf16x8 a[4][2];
#pragma unroll
    for (int s = 0; s < 4; ++s) {
        const float* qp = q + ((size_t)(bh * NSEQ + n0 + s * 16 + l16) * 64 + quad * 8);
#pragma unroll
        for (int kk = 0; kk < 2; ++kk) {
            a[s][kk] = load_cvt8(qp + kk * 32);
        }
    }

    const int   ucol = wave * 16 + l16;            // u offset within 64-wide tile
    const float scale = 0.125f;                    // 64^-0.5
    float* outb = out + ((size_t)bh * NSEQ) * NSEQ;

    for (int j = 0; j < 33; ++j) {
        const int u0   = n0 + j * 64;
        const int urow = u0 + ucol;                // E row index, <= 4095 < 4097

        // B fragment: B[k = quad*8+jj][col = lane&15] = E[urow][k]
        const float* ep = emb + ((size_t)urow * 64 + quad * 8);
        bf16x8 b0 = load_cvt8(ep);
        bf16x8 b1 = load_cvt8(ep + 32);

        f32x4 acc[4];
#pragma unroll
        for (int s = 0; s < 4; ++s) {
            acc[s] = (f32x4){0.f, 0.f, 0.f, 0.f};
            acc[s] = __builtin_amdgcn_mfma_f32_16x16x32_bf16(a[s][0], b0, acc[s], 0, 0, 0);
            acc[s] = __builtin_amdgcn_mfma_f32_16x16x32_bf16(a[s][1], b1, acc[s], 0, 0, 0);
        }

        // C/D layout: col = lane&15 (-> u = urow), row = quad*4 + t (+16s).
        // r = n + 2048 - u. Interior tiles (1..31) are always fully in-range.
        const int rbase = MAXS - urow + n0;        // r = rbase + (n - n0)
        if (j != 0 && j != 32) {
#pragma unroll
            for (int s = 0; s < 4; ++s) {
                const int nloc = s * 16 + quad * 4;
#pragma unroll
                for (int t = 0; t < 4; ++t) {
                    const int n = nloc + t;
                    outb[(size_t)(n0 + n) * NSEQ + (rbase + n)] = acc[s][t] * scale;
                }
            }
        } else {
#pragma unroll
            for (int s = 0; s < 4; ++s) {
                const int nloc = s * 16 + quad * 4;
#pragma unroll
                for (int t = 0; t < 4; ++t) {
                    const int n = nloc + t;
                    const int r = rbase + n;
                    if ((unsigned)r < (unsigned)NSEQ)
                        outb[(size_t)(n0 + n) * NSEQ + r] = acc[s][t] * scale;
                }
            }
        }
    }
}

extern "C" void kernel_launch(void* const* d_in, const int* in_sizes, int n_in,
                              void* d_out, int out_size, void* d_ws, size_t ws_size,
                              hipStream_t stream) {
    const float* q   = (const float*)d_in[0];
    // d_in[1] = k — unused by the reference forward.
    const float* emb = (const float*)d_in[2];   // [4097, 64]
    float* out = (float*)d_out;                 // [2, 16, 2048, 2048]

    dim3 grid(32, 32);   // x: n-tile, y: bh
    dim3 block(256);
    shaw_rel_pos_kernel<<<grid, block, 0, stream>>>(q, emb, out);
}